// Round 1
// baseline (294.024 us; speedup 1.0000x reference)
//
#include <hip/hip_runtime.h>

// MultiHeadSelfAttention: B=2, S=2048, D=1024, H=16, Dh=64, fp32 in/out.
// Strategy: full bf16-MFMA pipeline (threshold = max|ref|/50 ~ 5e-3, bf16-grade).
//  k1 cast fp32->bf16 (x, Wq,Wk,Wv,Wo)
//  k2 fused QKV NT-GEMM (m97 structure), epilogue -> [b,h,s,d]; Q *= log2e/8
//  k3 V -> V^T [b,h,d,s] (PV B-operand needs s contiguous)
//  k4 flash attention (online softmax, exp2, P via LDS round-trip)
//  k5 out-projection GEMM, fp32 + bias -> d_out
// Workspace: 48 MB.

#define T_TOK 4096
#define DM    1024
#define SQ    2048
#define NH    16
#define DH    64

typedef unsigned short u16;
typedef unsigned int   u32;
typedef __bf16 bf16x8 __attribute__((ext_vector_type(8)));
typedef float  f32x4  __attribute__((ext_vector_type(4)));

__device__ __forceinline__ u16 f2bf(float f) {   // RNE fp32->bf16
  u32 u = __builtin_bit_cast(u32, f);
  u32 r = (u + 0x7FFFu + ((u >> 16) & 1u)) >> 16;
  return (u16)r;
}

__device__ __forceinline__ void gld16(const void* g, void* l) {
  // async global->LDS, 16B/lane; LDS dest = wave-uniform base + lane*16
  __builtin_amdgcn_global_load_lds(
      (const __attribute__((address_space(1))) u32*)g,
      (__attribute__((address_space(3))) u32*)l, 16, 0, 0);
}

// ---------------- k1: cast to bf16 ----------------
__global__ void cast_bf16_kernel(const float* __restrict__ x,
    const float* __restrict__ w0, const float* __restrict__ w1,
    const float* __restrict__ w2, const float* __restrict__ w3,
    u16* __restrict__ xb, u16* __restrict__ o0, u16* __restrict__ o1,
    u16* __restrict__ o2, u16* __restrict__ o3)
{
  const float* src; u16* dst; int n;
  switch (blockIdx.y) {
    case 0:  src = x;  dst = xb; n = T_TOK * DM; break;
    case 1:  src = w0; dst = o0; n = DM * DM; break;
    case 2:  src = w1; dst = o1; n = DM * DM; break;
    case 3:  src = w2; dst = o2; n = DM * DM; break;
    default: src = w3; dst = o3; n = DM * DM; break;
  }
  const int stride = gridDim.x * blockDim.x;
  for (int i = blockIdx.x * blockDim.x + threadIdx.x; i * 4 < n; i += stride) {
    float4 v = ((const float4*)src)[i];
    ushort4 o;
    o.x = f2bf(v.x); o.y = f2bf(v.y); o.z = f2bf(v.z); o.w = f2bf(v.w);
    ((ushort4*)dst)[i] = o;
  }
}

// ---------------- shared 128x128 NT-GEMM core (K=1024, BK=32) ----------------
// Ab: A tile base (row-major, pitch DM), Bb: B^T tile base (row-major, pitch DM)
__device__ __forceinline__ void gemm_core_128x128(
    const u16* __restrict__ Ab, const u16* __restrict__ Bb, f32x4 acc[4][4])
{
  __shared__ __align__(16) u16 As[128 * 32];
  __shared__ __align__(16) u16 Bs[128 * 32];
  const int tid = threadIdx.x, lane = tid & 63, w = tid >> 6;
  const int waveM = w >> 1, waveN = w & 1;
  const int srow = lane >> 2, sch = lane & 3;      // staging: 16 rows x 4 chunks
  const int col = lane & 15, quad = lane >> 4;

  for (int k0 = 0; k0 < DM; k0 += 32) {
    #pragma unroll
    for (int i = 0; i < 2; ++i) {
      const int rb = w * 32 + i * 16;
      gld16(Ab + (size_t)(rb + srow) * DM + k0 + sch * 8, &As[rb * 32]);
      gld16(Bb + (size_t)(rb + srow) * DM + k0 + sch * 8, &Bs[rb * 32]);
    }
    __syncthreads();
    bf16x8 af[4], bg[4];
    #pragma unroll
    for (int i = 0; i < 4; ++i)
      af[i] = *(const bf16x8*)&As[(waveM * 64 + i * 16 + col) * 32 + quad * 8];
    #pragma unroll
    for (int j = 0; j < 4; ++j)
      bg[j] = *(const bf16x8*)&Bs[(waveN * 64 + j * 16 + col) * 32 + quad * 8];
    #pragma unroll
    for (int i = 0; i < 4; ++i) {
      #pragma unroll
      for (int j = 0; j < 4; ++j)
        acc[i][j] = __builtin_amdgcn_mfma_f32_16x16x32_bf16(af[i], bg[j], acc[i][j], 0, 0, 0);
    }
    __syncthreads();
  }
}

// ---------------- k2: fused QKV projection ----------------
__global__ __launch_bounds__(256) void gemm_qkv_kernel(
    const u16* __restrict__ xb,
    const u16* __restrict__ Wqb, const u16* __restrict__ Wkb, const u16* __restrict__ Wvb,
    const float* __restrict__ bq, const float* __restrict__ bk, const float* __restrict__ bv,
    u16* __restrict__ Qs, u16* __restrict__ Kh, u16* __restrict__ Vh)
{
  const int z = blockIdx.z;
  const u16*   Wb   = (z == 0) ? Wqb : (z == 1) ? Wkb : Wvb;
  const float* bias = (z == 0) ? bq  : (z == 1) ? bk  : bv;
  u16*         out  = (z == 0) ? Qs  : (z == 1) ? Kh  : Vh;
  const float scale = (z == 0) ? 0.18033688011112042f : 1.0f;  // log2(e)/8 for Q

  f32x4 acc[4][4];
  const f32x4 zf = {0.f, 0.f, 0.f, 0.f};
  #pragma unroll
  for (int i = 0; i < 4; ++i) {
    #pragma unroll
    for (int j = 0; j < 4; ++j) acc[i][j] = zf;
  }
  gemm_core_128x128(xb + (size_t)(blockIdx.y * 128) * DM,
                    Wb + (size_t)(blockIdx.x * 128) * DM, acc);

  const int lane = threadIdx.x & 63, w = threadIdx.x >> 6;
  const int waveM = w >> 1, waveN = w & 1;
  const int col = lane & 15, quad = lane >> 4;
  const int rowBase = blockIdx.y * 128 + waveM * 64;
  const int colBase = blockIdx.x * 128 + waveN * 64;
  #pragma unroll
  for (int j = 0; j < 4; ++j) {
    const int c = colBase + j * 16 + col;
    const float bb = bias[c];
    const int h = c >> 6, d = c & 63;
    #pragma unroll
    for (int i = 0; i < 4; ++i) {
      #pragma unroll
      for (int r = 0; r < 4; ++r) {
        const int t = rowBase + i * 16 + quad * 4 + r;       // token
        const int b = t >> 11, s = t & 2047;
        out[((size_t)(b * NH + h) * SQ + s) * DH + d] = f2bf((acc[i][j][r] + bb) * scale);
      }
    }
  }
}

// ---------------- k3: V [bh][s][d] -> V^T [bh][d][s] ----------------
__global__ __launch_bounds__(256) void transpose_v_kernel(
    const u16* __restrict__ Vh, u16* __restrict__ Vt)
{
  __shared__ u32 tile[64 * 65];
  const int bh = blockIdx.y, s0 = blockIdx.x * 64;
  const u16* src = Vh + ((size_t)bh * SQ + s0) * DH;
  u16* dst = Vt + (size_t)bh * DH * SQ + s0;
  for (int i = threadIdx.x; i < 64 * 64; i += 256) {
    int s = i >> 6, d = i & 63;
    tile[d * 65 + s] = src[(size_t)s * DH + d];
  }
  __syncthreads();
  for (int i = threadIdx.x; i < 64 * 64; i += 256) {
    int d = i >> 6, s = i & 63;
    dst[(size_t)d * SQ + s] = (u16)tile[d * 65 + s];
  }
}

// ---------------- k4: flash attention ----------------
// grid (S/128, B*H); block 256 (4 waves x 32 Q-rows). Q pre-scaled by log2e/8.
__global__ __launch_bounds__(256) void attn_kernel(
    const u16* __restrict__ Qs, const u16* __restrict__ Kh,
    const u16* __restrict__ Vt, u16* __restrict__ ctx)
{
  __shared__ __align__(16) u16 Qt[128 * 64];   // [q][d]   16KB
  __shared__ __align__(16) u16 Kt[64 * 64];    // [s'][d]   8KB
  __shared__ __align__(16) u16 Vl[64 * 64];    // [d][s']   8KB (from V^T)
  __shared__ __align__(16) u16 Pt[128 * 64];   // [q][s']  16KB
  const int tid = threadIdx.x, lane = tid & 63, w = tid >> 6;
  const int col = lane & 15, quad = lane >> 4;
  const int qrow = lane >> 3, qch = lane & 7;  // staging: 8 rows x 8 chunks
  const int bh = blockIdx.y, q0 = blockIdx.x * 128;
  const u16* Qb = Qs + ((size_t)bh * SQ + q0) * DH;
  const u16* Kb = Kh + (size_t)bh * SQ * DH;
  const u16* Vb = Vt + (size_t)bh * DH * SQ;

  #pragma unroll
  for (int i = 0; i < 4; ++i) {                // stage full Q tile once
    const int rb = w * 32 + i * 8;
    gld16(Qb + (size_t)(rb + qrow) * DH + qch * 8, &Qt[rb * DH]);
  }

  const f32x4 zf = {0.f, 0.f, 0.f, 0.f};
  f32x4 cacc[2][4];
  float m_i[2][4], l_i[2][4];
  #pragma unroll
  for (int t = 0; t < 2; ++t) {
    #pragma unroll
    for (int n = 0; n < 4; ++n) cacc[t][n] = zf;
    #pragma unroll
    for (int r = 0; r < 4; ++r) { m_i[t][r] = -1e30f; l_i[t][r] = 0.f; }
  }
  __syncthreads();

  for (int kt = 0; kt < SQ / 64; ++kt) {
    const int s0 = kt * 64;
    #pragma unroll
    for (int i = 0; i < 2; ++i) {              // stage K-tile + V-tile
      const int rb = w * 16 + i * 8;
      gld16(Kb + (size_t)(s0 + rb + qrow) * DH + qch * 8, &Kt[rb * DH]);
      gld16(Vb + (size_t)(rb + qrow) * SQ + s0 + qch * 8, &Vl[rb * DH]);
    }
    __syncthreads();

    // S = Q K^T (base-2 logits; scale folded into Q)
    f32x4 sacc[2][4];
    #pragma unroll
    for (int t = 0; t < 2; ++t) {
      #pragma unroll
      for (int n = 0; n < 4; ++n) sacc[t][n] = zf;
    }
    #pragma unroll
    for (int c = 0; c < 2; ++c) {
      bf16x8 aq[2], bk_[4];
      #pragma unroll
      for (int t = 0; t < 2; ++t)
        aq[t] = *(const bf16x8*)&Qt[(w * 32 + t * 16 + col) * DH + c * 32 + quad * 8];
      #pragma unroll
      for (int n = 0; n < 4; ++n)
        bk_[n] = *(const bf16x8*)&Kt[(n * 16 + col) * DH + c * 32 + quad * 8];
      #pragma unroll
      for (int t = 0; t < 2; ++t) {
        #pragma unroll
        for (int n = 0; n < 4; ++n)
          sacc[t][n] = __builtin_amdgcn_mfma_f32_16x16x32_bf16(aq[t], bk_[n], sacc[t][n], 0, 0, 0);
      }
    }

    // online softmax; C-layout row = quad*4+r, col = n*16 + (lane&15)
    #pragma unroll
    for (int t = 0; t < 2; ++t) {
      float mx[4];
      #pragma unroll
      for (int r = 0; r < 4; ++r)
        mx[r] = fmaxf(fmaxf(sacc[t][0][r], sacc[t][1][r]),
                      fmaxf(sacc[t][2][r], sacc[t][3][r]));
      #pragma unroll
      for (int m = 1; m <= 8; m <<= 1) {
        #pragma unroll
        for (int r = 0; r < 4; ++r)
          mx[r] = fmaxf(mx[r], __shfl_xor(mx[r], m, 64));
      }
      float alpha[4];
      #pragma unroll
      for (int r = 0; r < 4; ++r) {
        const float mn = fmaxf(m_i[t][r], mx[r]);
        alpha[r] = __builtin_amdgcn_exp2f(m_i[t][r] - mn);
        m_i[t][r] = mn;
      }
      float rs[4] = {0.f, 0.f, 0.f, 0.f};
      #pragma unroll
      for (int n = 0; n < 4; ++n) {
        #pragma unroll
        for (int r = 0; r < 4; ++r) {
          const float p = __builtin_amdgcn_exp2f(sacc[t][n][r] - m_i[t][r]);
          sacc[t][n][r] = p;
          rs[r] += p;
        }
      }
      #pragma unroll
      for (int m = 1; m <= 8; m <<= 1) {
        #pragma unroll
        for (int r = 0; r < 4; ++r)
          rs[r] += __shfl_xor(rs[r], m, 64);
      }
      #pragma unroll
      for (int r = 0; r < 4; ++r)
        l_i[t][r] = l_i[t][r] * alpha[r] + rs[r];
      #pragma unroll
      for (int n = 0; n < 4; ++n) {
        #pragma unroll
        for (int r = 0; r < 4; ++r)
          cacc[t][n][r] *= alpha[r];
      }
      // P -> LDS (bf16), wave-private region; read back in A-operand layout
      #pragma unroll
      for (int n = 0; n < 4; ++n) {
        #pragma unroll
        for (int r = 0; r < 4; ++r)
          Pt[(w * 32 + t * 16 + quad * 4 + r) * 64 + n * 16 + col] = f2bf(sacc[t][n][r]);
      }
    }

    // ctx += P V
    #pragma unroll
    for (int c = 0; c < 2; ++c) {
      bf16x8 ap[2], bv_[4];
      #pragma unroll
      for (int t = 0; t < 2; ++t)
        ap[t] = *(const bf16x8*)&Pt[(w * 32 + t * 16 + col) * 64 + c * 32 + quad * 8];
      #pragma unroll
      for (int n = 0; n < 4; ++n)
        bv_[n] = *(const bf16x8*)&Vl[(n * 16 + col) * 64 + c * 32 + quad * 8];
      #pragma unroll
      for (int t = 0; t < 2; ++t) {
        #pragma unroll
        for (int n = 0; n < 4; ++n)
          cacc[t][n] = __builtin_amdgcn_mfma_f32_16x16x32_bf16(ap[t], bv_[n], cacc[t][n], 0, 0, 0);
      }
    }
    __syncthreads();   // protect K/V/P tiles before next stage
  }

  // epilogue: ctx[token][h*64+d] bf16
  const int b = bh >> 4, h = bh & 15;
  #pragma unroll
  for (int t = 0; t < 2; ++t) {
    float inv[4];
    #pragma unroll
    for (int r = 0; r < 4; ++r) inv[r] = 1.0f / l_i[t][r];
    #pragma unroll
    for (int n = 0; n < 4; ++n) {
      #pragma unroll
      for (int r = 0; r < 4; ++r) {
        const int s = q0 + w * 32 + t * 16 + quad * 4 + r;
        ctx[(size_t)(b * SQ + s) * DM + h * DH + n * 16 + col] =
            f2bf(cacc[t][n][r] * inv[r]);
      }
    }
  }
}

// ---------------- k5: output projection (fp32 out + bias) ----------------
__global__ __launch_bounds__(256) void gemm_out_kernel(
    const u16* __restrict__ ctx, const u16* __restrict__ Wob,
    const float* __restrict__ bo, float* __restrict__ out)
{
  f32x4 acc[4][4];
  const f32x4 zf = {0.f, 0.f, 0.f, 0.f};
  #pragma unroll
  for (int i = 0; i < 4; ++i) {
    #pragma unroll
    for (int j = 0; j < 4; ++j) acc[i][j] = zf;
  }
  gemm_core_128x128(ctx + (size_t)(blockIdx.y * 128) * DM,
                    Wob + (size_t)(blockIdx.x * 128) * DM, acc);

  const int lane = threadIdx.x & 63, w = threadIdx.x >> 6;
  const int waveM = w >> 1, waveN = w & 1;
  const int col = lane & 15, quad = lane >> 4;
  const int rowBase = blockIdx.y * 128 + waveM * 64;
  const int colBase = blockIdx.x * 128 + waveN * 64;
  #pragma unroll
  for (int j = 0; j < 4; ++j) {
    const int c = colBase + j * 16 + col;
    const float bb = bo[c];
    #pragma unroll
    for (int i = 0; i < 4; ++i) {
      #pragma unroll
      for (int r = 0; r < 4; ++r) {
        const int t = rowBase + i * 16 + quad * 4 + r;
        out[(size_t)t * DM + c] = acc[i][j][r] + bb;
      }
    }
  }
}

extern "C" void kernel_launch(void* const* d_in, const int* in_sizes, int n_in,
                              void* d_out, int out_size, void* d_ws, size_t ws_size,
                              hipStream_t stream) {
  const float* x  = (const float*)d_in[0];
  const float* Wq = (const float*)d_in[1];
  const float* bq = (const float*)d_in[2];
  const float* Wk = (const float*)d_in[3];
  const float* bk = (const float*)d_in[4];
  const float* Wv = (const float*)d_in[5];
  const float* bv = (const float*)d_in[6];
  const float* Wo = (const float*)d_in[7];
  const float* bo = (const float*)d_in[8];

  char* ws = (char*)d_ws;                  // 48 MB used
  u16* xb  = (u16*)(ws);                   // 8 MB  (reused as ctx after QKV)
  u16* Wqb = (u16*)(ws + (8ull  << 20));   // 2 MB
  u16* Wkb = (u16*)(ws + (10ull << 20));   // 2 MB
  u16* Wvb = (u16*)(ws + (12ull << 20));   // 2 MB
  u16* Wob = (u16*)(ws + (14ull << 20));   // 2 MB
  u16* Qs  = (u16*)(ws + (16ull << 20));   // 8 MB  [b,h,s,d], pre-scaled
  u16* Kh  = (u16*)(ws + (24ull << 20));   // 8 MB  [b,h,s,d]
  u16* Vh  = (u16*)(ws + (32ull << 20));   // 8 MB  [b,h,s,d]
  u16* Vt  = (u16*)(ws + (40ull << 20));   // 8 MB  [b,h,d,s]
  u16* ctx = xb;                           // alias: xb dead after QKV GEMM

  cast_bf16_kernel<<<dim3(256, 5), 256, 0, stream>>>(x, Wq, Wk, Wv, Wo,
                                                     xb, Wqb, Wkb, Wvb, Wob);
  gemm_qkv_kernel<<<dim3(8, 32, 3), 256, 0, stream>>>(xb, Wqb, Wkb, Wvb,
                                                      bq, bk, bv, Qs, Kh, Vh);
  transpose_v_kernel<<<dim3(32, 32), 256, 0, stream>>>(Vh, Vt);
  attn_kernel<<<dim3(16, 32), 256, 0, stream>>>(Qs, Kh, Vt, ctx);
  gemm_out_kernel<<<dim3(8, 32), 256, 0, stream>>>(ctx, Wob, bo, (float*)d_out);
  (void)in_sizes; (void)n_in; (void)out_size; (void)ws_size;
}

// Round 2
// 225.418 us; speedup vs baseline: 1.3044x; 1.3044x over previous
//
#include <hip/hip_runtime.h>

// MultiHeadSelfAttention: B=2, S=2048, D=1024, H=16, Dh=64, fp32 in/out.
// bf16-MFMA pipeline. R2: attn rewritten — S^T formulation (K*Q^T), XOR-swizzled
// LDS staging, register-resident Q, double-buffered K/V (1 barrier/iter),
// vectorized P/ctx stores, column-softmax (2 shuffles instead of 8 per tile).

#define T_TOK 4096
#define DM    1024
#define SQ    2048
#define NH    16
#define DH    64

typedef unsigned short u16;
typedef unsigned int   u32;
typedef __bf16 bf16x8 __attribute__((ext_vector_type(8)));
typedef float  f32x4  __attribute__((ext_vector_type(4)));

__device__ __forceinline__ u16 f2bf(float f) {   // RNE fp32->bf16
  u32 u = __builtin_bit_cast(u32, f);
  u32 r = (u + 0x7FFFu + ((u >> 16) & 1u)) >> 16;
  return (u16)r;
}

__device__ __forceinline__ void gld16(const void* g, void* l) {
  // async global->LDS, 16B/lane; LDS dest = wave-uniform base + lane*16
  __builtin_amdgcn_global_load_lds(
      (const __attribute__((address_space(1))) u32*)g,
      (__attribute__((address_space(3))) u32*)l, 16, 0, 0);
}

// ---------------- k1: cast to bf16 ----------------
__global__ void cast_bf16_kernel(const float* __restrict__ x,
    const float* __restrict__ w0, const float* __restrict__ w1,
    const float* __restrict__ w2, const float* __restrict__ w3,
    u16* __restrict__ xb, u16* __restrict__ o0, u16* __restrict__ o1,
    u16* __restrict__ o2, u16* __restrict__ o3)
{
  const float* src; u16* dst; int n;
  switch (blockIdx.y) {
    case 0:  src = x;  dst = xb; n = T_TOK * DM; break;
    case 1:  src = w0; dst = o0; n = DM * DM; break;
    case 2:  src = w1; dst = o1; n = DM * DM; break;
    case 3:  src = w2; dst = o2; n = DM * DM; break;
    default: src = w3; dst = o3; n = DM * DM; break;
  }
  const int stride = gridDim.x * blockDim.x;
  for (int i = blockIdx.x * blockDim.x + threadIdx.x; i * 4 < n; i += stride) {
    float4 v = ((const float4*)src)[i];
    ushort4 o;
    o.x = f2bf(v.x); o.y = f2bf(v.y); o.z = f2bf(v.z); o.w = f2bf(v.w);
    ((ushort4*)dst)[i] = o;
  }
}

// ---------------- shared 128x128 NT-GEMM core (K=1024, BK=32) ----------------
__device__ __forceinline__ void gemm_core_128x128(
    const u16* __restrict__ Ab, const u16* __restrict__ Bb, f32x4 acc[4][4])
{
  __shared__ __align__(16) u16 As[128 * 32];
  __shared__ __align__(16) u16 Bs[128 * 32];
  const int tid = threadIdx.x, lane = tid & 63, w = tid >> 6;
  const int waveM = w >> 1, waveN = w & 1;
  const int srow = lane >> 2, sch = lane & 3;      // staging: 16 rows x 4 chunks
  const int col = lane & 15, quad = lane >> 4;

  for (int k0 = 0; k0 < DM; k0 += 32) {
    #pragma unroll
    for (int i = 0; i < 2; ++i) {
      const int rb = w * 32 + i * 16;
      gld16(Ab + (size_t)(rb + srow) * DM + k0 + sch * 8, &As[rb * 32]);
      gld16(Bb + (size_t)(rb + srow) * DM + k0 + sch * 8, &Bs[rb * 32]);
    }
    __syncthreads();
    bf16x8 af[4], bg[4];
    #pragma unroll
    for (int i = 0; i < 4; ++i)
      af[i] = *(const bf16x8*)&As[(waveM * 64 + i * 16 + col) * 32 + quad * 8];
    #pragma unroll
    for (int j = 0; j < 4; ++j)
      bg[j] = *(const bf16x8*)&Bs[(waveN * 64 + j * 16 + col) * 32 + quad * 8];
    #pragma unroll
    for (int i = 0; i < 4; ++i) {
      #pragma unroll
      for (int j = 0; j < 4; ++j)
        acc[i][j] = __builtin_amdgcn_mfma_f32_16x16x32_bf16(af[i], bg[j], acc[i][j], 0, 0, 0);
    }
    __syncthreads();
  }
}

// ---------------- k2: fused QKV projection ----------------
__global__ __launch_bounds__(256) void gemm_qkv_kernel(
    const u16* __restrict__ xb,
    const u16* __restrict__ Wqb, const u16* __restrict__ Wkb, const u16* __restrict__ Wvb,
    const float* __restrict__ bq, const float* __restrict__ bk, const float* __restrict__ bv,
    u16* __restrict__ Qs, u16* __restrict__ Kh, u16* __restrict__ Vh)
{
  const int z = blockIdx.z;
  const u16*   Wb   = (z == 0) ? Wqb : (z == 1) ? Wkb : Wvb;
  const float* bias = (z == 0) ? bq  : (z == 1) ? bk  : bv;
  u16*         out  = (z == 0) ? Qs  : (z == 1) ? Kh  : Vh;
  const float scale = (z == 0) ? 0.18033688011112042f : 1.0f;  // log2(e)/8 for Q

  f32x4 acc[4][4];
  const f32x4 zf = {0.f, 0.f, 0.f, 0.f};
  #pragma unroll
  for (int i = 0; i < 4; ++i) {
    #pragma unroll
    for (int j = 0; j < 4; ++j) acc[i][j] = zf;
  }
  gemm_core_128x128(xb + (size_t)(blockIdx.y * 128) * DM,
                    Wb + (size_t)(blockIdx.x * 128) * DM, acc);

  const int lane = threadIdx.x & 63, w = threadIdx.x >> 6;
  const int waveM = w >> 1, waveN = w & 1;
  const int col = lane & 15, quad = lane >> 4;
  const int rowBase = blockIdx.y * 128 + waveM * 64;
  const int colBase = blockIdx.x * 128 + waveN * 64;
  #pragma unroll
  for (int j = 0; j < 4; ++j) {
    const int c = colBase + j * 16 + col;
    const float bb = bias[c];
    const int h = c >> 6, d = c & 63;
    #pragma unroll
    for (int i = 0; i < 4; ++i) {
      #pragma unroll
      for (int r = 0; r < 4; ++r) {
        const int t = rowBase + i * 16 + quad * 4 + r;       // token
        const int b = t >> 11, s = t & 2047;
        out[((size_t)(b * NH + h) * SQ + s) * DH + d] = f2bf((acc[i][j][r] + bb) * scale);
      }
    }
  }
}

// ---------------- k3: V [bh][s][d] -> V^T [bh][d][s] ----------------
__global__ __launch_bounds__(256) void transpose_v_kernel(
    const u16* __restrict__ Vh, u16* __restrict__ Vt)
{
  __shared__ u32 tile[64 * 65];
  const int bh = blockIdx.y, s0 = blockIdx.x * 64;
  const u16* src = Vh + ((size_t)bh * SQ + s0) * DH;
  u16* dst = Vt + (size_t)bh * DH * SQ + s0;
  for (int i = threadIdx.x; i < 64 * 64; i += 256) {
    int s = i >> 6, d = i & 63;
    tile[d * 65 + s] = src[(size_t)s * DH + d];
  }
  __syncthreads();
  for (int i = threadIdx.x; i < 64 * 64; i += 256) {
    int d = i >> 6, s = i & 63;
    dst[(size_t)d * SQ + s] = (u16)tile[d * 65 + s];
  }
}

// ---------------- k4: flash attention (S^T formulation) ----------------
// grid (S/128, B*H); block 256 = 4 waves; wave w owns q-range [w*32, w*32+32).
// S^T = K Q^T (A=K-tile, B=Q-frags in regs); softmax per q-column;
// P^T -> LDS via b64 writes; ctx^T = V^T P^T (A=Vl, B=Pt).
// All LDS tiles 64-u16 pitch with XOR granule swizzle g' = g ^ (row&7),
// applied at the GLOBAL source address for global_load_lds staging.
__global__ __launch_bounds__(256, 2) void attn_kernel(
    const u16* __restrict__ Qs, const u16* __restrict__ Kh,
    const u16* __restrict__ Vt, u16* __restrict__ ctx)
{
  __shared__ __align__(16) u16 Kt[2][64 * 64];   // [s'][d]  2x8KB
  __shared__ __align__(16) u16 Vl[2][64 * 64];   // [d][s']  2x8KB
  __shared__ __align__(16) u16 Pt[128 * 64];     // [q][s']  16KB
  const int tid = threadIdx.x, lane = tid & 63, w = tid >> 6;
  const int col = lane & 15, quad = lane >> 4;
  const int srow = lane >> 3;                    // staging row 0..7
  const int sgrn = (lane & 7) ^ srow;            // swizzled source granule
  const int bh = blockIdx.y, q0 = blockIdx.x * 128;
  const u16* Qb = Qs + ((size_t)bh * SQ + q0) * DH;
  const u16* Kb = Kh + (size_t)bh * SQ * DH;
  const u16* Vb = Vt + (size_t)bh * DH * SQ;
  const int sw = col & 7;                        // read-side swizzle key

  // Q fragments once, direct from global (B-operand layout)
  bf16x8 qreg[2][2];
  #pragma unroll
  for (int nt = 0; nt < 2; ++nt) {
    #pragma unroll
    for (int c = 0; c < 2; ++c)
      qreg[nt][c] = *(const bf16x8*)(Qb + (size_t)(w * 32 + nt * 16 + col) * DH
                                        + c * 32 + quad * 8);
  }

  // stage K/V tile 0 (wave stages 16 rows each; rows 8-aligned so row&7 = srow)
  #pragma unroll
  for (int i = 0; i < 2; ++i) {
    const int rb = w * 16 + i * 8;
    gld16(Kb + (size_t)(rb + srow) * DH + sgrn * 8, &Kt[0][rb * 64]);
    gld16(Vb + (size_t)(rb + srow) * SQ + sgrn * 8, &Vl[0][rb * 64]);
  }

  const f32x4 zf = {0.f, 0.f, 0.f, 0.f};
  f32x4 cacc[4][2];                 // [d-tile][q-tile], ctx^T accumulator
  float m_s[2], l_s[2];
  #pragma unroll
  for (int mt = 0; mt < 4; ++mt) {
    #pragma unroll
    for (int nt = 0; nt < 2; ++nt) cacc[mt][nt] = zf;
  }
  m_s[0] = m_s[1] = -1e30f; l_s[0] = l_s[1] = 0.f;
  __syncthreads();

  for (int kt = 0; kt < SQ / 64; ++kt) {
    const int cur = kt & 1;
    if (kt + 1 < SQ / 64) {                      // prefetch next K/V tile
      const int nxt = cur ^ 1, s1 = (kt + 1) * 64;
      #pragma unroll
      for (int i = 0; i < 2; ++i) {
        const int rb = w * 16 + i * 8;
        gld16(Kb + (size_t)(s1 + rb + srow) * DH + sgrn * 8, &Kt[nxt][rb * 64]);
        gld16(Vb + (size_t)(rb + srow) * SQ + s1 + sgrn * 8, &Vl[nxt][rb * 64]);
      }
    }

    // S^T = K Q^T : sacc[mt][nt], rows s' = mt*16+quad*4+r, cols q = nt*16+col
    f32x4 sacc[4][2];
    #pragma unroll
    for (int mt = 0; mt < 4; ++mt) {
      #pragma unroll
      for (int nt = 0; nt < 2; ++nt) sacc[mt][nt] = zf;
    }
    #pragma unroll
    for (int c = 0; c < 2; ++c) {
      bf16x8 ak[4];
      #pragma unroll
      for (int mt = 0; mt < 4; ++mt)
        ak[mt] = *(const bf16x8*)&Kt[cur][(mt * 16 + col) * 64
                                          + (((c * 4 + quad) ^ sw) * 8)];
      #pragma unroll
      for (int mt = 0; mt < 4; ++mt) {
        #pragma unroll
        for (int nt = 0; nt < 2; ++nt)
          sacc[mt][nt] = __builtin_amdgcn_mfma_f32_16x16x32_bf16(
              ak[mt], qreg[nt][c], sacc[mt][nt], 0, 0, 0);
      }
    }

    // online softmax per q-column (q = w*32+nt*16+col)
    #pragma unroll
    for (int nt = 0; nt < 2; ++nt) {
      float mx = sacc[0][nt][0];
      #pragma unroll
      for (int mt = 0; mt < 4; ++mt) {
        #pragma unroll
        for (int r = 0; r < 4; ++r) mx = fmaxf(mx, sacc[mt][nt][r]);
      }
      mx = fmaxf(mx, __shfl_xor(mx, 16, 64));
      mx = fmaxf(mx, __shfl_xor(mx, 32, 64));
      const float mn = fmaxf(m_s[nt], mx);
      const float alpha = __builtin_amdgcn_exp2f(m_s[nt] - mn);
      m_s[nt] = mn;
      float rs = 0.f;
      #pragma unroll
      for (int mt = 0; mt < 4; ++mt) {
        #pragma unroll
        for (int r = 0; r < 4; ++r) {
          const float p = __builtin_amdgcn_exp2f(sacc[mt][nt][r] - mn);
          sacc[mt][nt][r] = p;
          rs += p;
        }
      }
      rs += __shfl_xor(rs, 16, 64);
      rs += __shfl_xor(rs, 32, 64);
      l_s[nt] = l_s[nt] * alpha + rs;
      #pragma unroll
      for (int mt = 0; mt < 4; ++mt) {
        #pragma unroll
        for (int r = 0; r < 4; ++r) cacc[mt][nt][r] *= alpha;
      }
      // P^T -> Pt[q][s'] : 4 consecutive s' per lane -> one b64 write
      const int qrow = w * 32 + nt * 16 + col;
      #pragma unroll
      for (int mt = 0; mt < 4; ++mt) {
        ushort4 pk;
        pk.x = f2bf(sacc[mt][nt][0]); pk.y = f2bf(sacc[mt][nt][1]);
        pk.z = f2bf(sacc[mt][nt][2]); pk.w = f2bf(sacc[mt][nt][3]);
        *(ushort4*)&Pt[qrow * 64 + (((mt * 2 + (quad >> 1)) ^ sw) * 8)
                       + (quad & 1) * 4] = pk;
      }
    }

    // ctx^T += V^T P^T : A = Vl (d x s'), B = Pt (q x s')
    #pragma unroll
    for (int c = 0; c < 2; ++c) {
      bf16x8 av[4], bp[2];
      #pragma unroll
      for (int mt = 0; mt < 4; ++mt)
        av[mt] = *(const bf16x8*)&Vl[cur][(mt * 16 + col) * 64
                                          + (((c * 4 + quad) ^ sw) * 8)];
      #pragma unroll
      for (int nt = 0; nt < 2; ++nt)
        bp[nt] = *(const bf16x8*)&Pt[(w * 32 + nt * 16 + col) * 64
                                     + (((c * 4 + quad) ^ sw) * 8)];
      #pragma unroll
      for (int mt = 0; mt < 4; ++mt) {
        #pragma unroll
        for (int nt = 0; nt < 2; ++nt)
          cacc[mt][nt] = __builtin_amdgcn_mfma_f32_16x16x32_bf16(
              av[mt], bp[nt], cacc[mt][nt], 0, 0, 0);
      }
    }
    __syncthreads();   // K/V buffer reuse fence + prefetch drain
  }

  // epilogue: lane holds (d = mt*16+quad*4+r, q = w*32+nt*16+col)
  const int b = bh >> 4, h = bh & 15;
  #pragma unroll
  for (int nt = 0; nt < 2; ++nt) {
    const float inv = 1.0f / l_s[nt];
    const int s = q0 + w * 32 + nt * 16 + col;
    #pragma unroll
    for (int mt = 0; mt < 4; ++mt) {
      ushort4 pk;
      pk.x = f2bf(cacc[mt][nt][0] * inv); pk.y = f2bf(cacc[mt][nt][1] * inv);
      pk.z = f2bf(cacc[mt][nt][2] * inv); pk.w = f2bf(cacc[mt][nt][3] * inv);
      *(ushort4*)&ctx[(size_t)(b * SQ + s) * DM + h * DH + mt * 16 + quad * 4] = pk;
    }
  }
}

// ---------------- k5: output projection (fp32 out + bias) ----------------
__global__ __launch_bounds__(256) void gemm_out_kernel(
    const u16* __restrict__ ctx, const u16* __restrict__ Wob,
    const float* __restrict__ bo, float* __restrict__ out)
{
  f32x4 acc[4][4];
  const f32x4 zf = {0.f, 0.f, 0.f, 0.f};
  #pragma unroll
  for (int i = 0; i < 4; ++i) {
    #pragma unroll
    for (int j = 0; j < 4; ++j) acc[i][j] = zf;
  }
  gemm_core_128x128(ctx + (size_t)(blockIdx.y * 128) * DM,
                    Wob + (size_t)(blockIdx.x * 128) * DM, acc);

  const int lane = threadIdx.x & 63, w = threadIdx.x >> 6;
  const int waveM = w >> 1, waveN = w & 1;
  const int col = lane & 15, quad = lane >> 4;
  const int rowBase = blockIdx.y * 128 + waveM * 64;
  const int colBase = blockIdx.x * 128 + waveN * 64;
  #pragma unroll
  for (int j = 0; j < 4; ++j) {
    const int c = colBase + j * 16 + col;
    const float bb = bo[c];
    #pragma unroll
    for (int i = 0; i < 4; ++i) {
      #pragma unroll
      for (int r = 0; r < 4; ++r) {
        const int t = rowBase + i * 16 + quad * 4 + r;
        out[(size_t)t * DM + c] = acc[i][j][r] + bb;
      }
    }
  }
}

extern "C" void kernel_launch(void* const* d_in, const int* in_sizes, int n_in,
                              void* d_out, int out_size, void* d_ws, size_t ws_size,
                              hipStream_t stream) {
  const float* x  = (const float*)d_in[0];
  const float* Wq = (const float*)d_in[1];
  const float* bq = (const float*)d_in[2];
  const float* Wk = (const float*)d_in[3];
  const float* bk = (const float*)d_in[4];
  const float* Wv = (const float*)d_in[5];
  const float* bv = (const float*)d_in[6];
  const float* Wo = (const float*)d_in[7];
  const float* bo = (const float*)d_in[8];

  char* ws = (char*)d_ws;                  // 48 MB used
  u16* xb  = (u16*)(ws);                   // 8 MB  (reused as ctx after QKV)
  u16* Wqb = (u16*)(ws + (8ull  << 20));   // 2 MB
  u16* Wkb = (u16*)(ws + (10ull << 20));   // 2 MB
  u16* Wvb = (u16*)(ws + (12ull << 20));   // 2 MB
  u16* Wob = (u16*)(ws + (14ull << 20));   // 2 MB
  u16* Qs  = (u16*)(ws + (16ull << 20));   // 8 MB  [b,h,s,d], pre-scaled
  u16* Kh  = (u16*)(ws + (24ull << 20));   // 8 MB  [b,h,s,d]
  u16* Vh  = (u16*)(ws + (32ull << 20));   // 8 MB  [b,h,s,d]
  u16* Vt  = (u16*)(ws + (40ull << 20));   // 8 MB  [b,h,d,s]
  u16* ctx = xb;                           // alias: xb dead after QKV GEMM

  cast_bf16_kernel<<<dim3(256, 5), 256, 0, stream>>>(x, Wq, Wk, Wv, Wo,
                                                     xb, Wqb, Wkb, Wvb, Wob);
  gemm_qkv_kernel<<<dim3(8, 32, 3), 256, 0, stream>>>(xb, Wqb, Wkb, Wvb,
                                                      bq, bk, bv, Qs, Kh, Vh);
  transpose_v_kernel<<<dim3(32, 32), 256, 0, stream>>>(Vh, Vt);
  attn_kernel<<<dim3(16, 32), 256, 0, stream>>>(Qs, Kh, Vt, ctx);
  gemm_out_kernel<<<dim3(8, 32), 256, 0, stream>>>(ctx, Wob, bo, (float*)d_out);
  (void)in_sizes; (void)n_in; (void)out_size; (void)ws_size;
}